// Round 2
// baseline (556.755 us; speedup 1.0000x reference)
//
#include <hip/hip_runtime.h>
#include <hip/hip_bf16.h>

// RNN: B=1024, T=512, H=128, +4 autoregressive steps -> out (1024, 516)
// Round 2: runtime dtype detection (fp32 vs bf16 inputs) + same fp32 VALU core.
//  - detect kernel: reads fc_w as bf16; fp32-data-as-bf16 shows NaN/huge values
//  - main kernel: block-uniform branch into fp32/bf16 template specialization
//  - 2 batch rows per block, 128 hidden units -> 256 threads, 512 blocks
//  - W row (128 fp32) in registers (full unroll); h double-buffered in LDS

#define BB 1024
#define TT 512
#define HH 128
#define TPRED 4
#define TOUT (TT + TPRED)  // 516
#define ROWS 2             // rows per block

__global__ void detect_dtype(const void* w, int* flag) {
    const int lane = threadIdx.x;  // 64 threads
    const __hip_bfloat16* p = (const __hip_bfloat16*)w;
    const float v0 = __bfloat162float(p[lane]);
    const float v1 = __bfloat162float(p[64 + lane]);
    // NaN fails (fabs < 100), so `bad` is true for NaN and huge values
    const bool bad = !(fabsf(v0) < 100.0f) || !(fabsf(v1) < 100.0f);
    const unsigned long long m = __ballot(bad);
    if (lane == 0) *flag = (__popcll(m) > 4) ? 1 : 0;  // 1 => data is fp32
}

template <bool F32>
__device__ __forceinline__ float ld(const void* p, int idx) {
    if (F32) return ((const float*)p)[idx];
    return __bfloat162float(((const __hip_bfloat16*)p)[idx]);
}

template <bool F32>
__device__ __forceinline__ void rnn_body(
    const void* __restrict__ xg, const void* __restrict__ h0,
    const void* __restrict__ w0, const void* __restrict__ b0,
    const void* __restrict__ W,  const void* __restrict__ bw,
    const void* __restrict__ dw, const void* __restrict__ db,
    void* __restrict__ out,
    float (*xs)[TT], float (*hs0)[ROWS][HH], float* wpart, float* ys)
{
    const int tid  = threadIdx.x;
    const int i    = tid & (HH - 1);     // hidden unit
    const int r    = tid >> 7;           // row within block (wave-uniform)
    const int rowg = blockIdx.x * ROWS + r;
    const int lane = tid & 63;
    const int wid  = tid >> 6;           // 0..3

    // stage x for this block's rows (one-time)
    for (int idx = tid; idx < ROWS * TT; idx += 256) {
        const int rr = idx >> 9;         // /512
        const int t2 = idx & (TT - 1);
        xs[rr][t2] = ld<F32>(xg, (blockIdx.x * ROWS + rr) * TT + t2);
    }
    // init hidden state
    hs0[0][r][i] = ld<F32>(h0, rowg * HH + i);
    if (tid < ROWS) ys[tid] = 0.0f;

    // per-thread constants: W row i in registers, biases, decoder weight
    float wreg[HH];
    #pragma unroll
    for (int j = 0; j < HH; ++j) wreg[j] = ld<F32>(W, i * HH + j);
    const float w0v  = ld<F32>(w0, i);
    const float bsum = ld<F32>(b0, i) + ld<F32>(bw, i);
    const float dwv  = ld<F32>(dw, i);
    const float dbv  = ld<F32>(db, 0);

    __syncthreads();

    int buf = 0;
    #pragma unroll 1
    for (int t = 0; t < TOUT; ++t) {
        const int tc = (t < TT) ? t : 0;
        const float xv = (t < TT) ? xs[r][tc] : ys[r];
        float acc = fmaf(xv, w0v, bsum);
        const float* hb = hs0[buf][r];
        #pragma unroll
        for (int j = 0; j < HH; ++j) acc = fmaf(wreg[j], hb[j], acc);
        // tanh(acc) = 1 - 2/(exp(2*acc)+1)  (saturates correctly at +/-inf)
        const float e = __expf(acc + acc);
        const float h = 1.0f - __fdividef(2.0f, e + 1.0f);
        hs0[buf ^ 1][r][i] = h;
        // decoder: y[r] = sum_i h*dw[i] + db ; butterfly over 64 lanes
        float p = h * dwv;
        #pragma unroll
        for (int off = 32; off > 0; off >>= 1) p += __shfl_xor(p, off);
        if (lane == 0) wpart[wid] = p;
        __syncthreads();
        if (i == 0) {
            const float y = wpart[r * 2] + wpart[r * 2 + 1] + dbv;
            ys[r] = y;
            const int o = rowg * TOUT + t;
            if (F32) ((float*)out)[o] = y;
            else     ((__hip_bfloat16*)out)[o] = __float2bfloat16(y);
        }
        __syncthreads();
        buf ^= 1;
    }
}

__global__ __launch_bounds__(256, 2)
void rnn_kernel(const void* __restrict__ xg, const void* __restrict__ h0,
                const void* __restrict__ w0, const void* __restrict__ b0,
                const void* __restrict__ W,  const void* __restrict__ bw,
                const void* __restrict__ dw, const void* __restrict__ db,
                void* __restrict__ out, const int* __restrict__ flag)
{
    __shared__ float xs[ROWS][TT];       // staged input series per row
    __shared__ float hs[2][ROWS][HH];    // double-buffered hidden state
    __shared__ float wpart[4];           // per-wave decoder partials
    __shared__ float ys[ROWS];           // decoder output (feedback)

    const int f = *(volatile const int*)flag;  // block-uniform
    if (f) rnn_body<true >(xg, h0, w0, b0, W, bw, dw, db, out, xs, hs, wpart, ys);
    else   rnn_body<false>(xg, h0, w0, b0, W, bw, dw, db, out, xs, hs, wpart, ys);
}

extern "C" void kernel_launch(void* const* d_in, const int* in_sizes, int n_in,
                              void* d_out, int out_size, void* d_ws, size_t ws_size,
                              hipStream_t stream) {
    int* flag = (int*)d_ws;
    detect_dtype<<<1, 64, 0, stream>>>(d_in[4], flag);  // probe fc_w
    rnn_kernel<<<BB / ROWS, 256, 0, stream>>>(d_in[0], d_in[1], d_in[2], d_in[3],
                                              d_in[4], d_in[5], d_in[6], d_in[7],
                                              d_out, flag);
}

// Round 3
// 342.154 us; speedup vs baseline: 1.6272x; 1.6272x over previous
//
#include <hip/hip_runtime.h>
#include <hip/hip_bf16.h>

// RNN: B=1024, T=512, H=128, +4 autoregressive steps -> out (1024, 516)
// Round 3: MFMA formulation. Per step: h_new^T = tanh(W·h^T + x·w0^T + b).
//  - 64 blocks × 256 thr (4 waves); block owns 16 batch rows.
//  - W as MFMA A-operand, preloaded in registers, split hi+lo bf16 (fp32-exact W).
//  - h in LDS [16 batch][136 bf16] (pad 8 -> 2-way bank aliasing only), dbl-buffered.
//  - One __syncthreads per step; decoder dot fused (shfl + LDS partials, dbl-buffered).
//  - dtype-detect mechanism kept from round 2 (observed: fp32 inputs/out).

#define BB 1024
#define TT 512
#define HH 128
#define TOUT 516
#define BM 16          // batch rows per block
#define NW 4           // waves per block
#define MTW 2          // 16-col m-tiles per wave (4*2*16 = 128 = HH)
#define HSTR 136       // padded h stride in bf16 elems (272 B)

typedef __attribute__((ext_vector_type(8))) short bf16x8;
typedef __attribute__((ext_vector_type(4))) short short4_t;
typedef __attribute__((ext_vector_type(4))) float f32x4;

__device__ __forceinline__ short f2bs(float f) {
    __hip_bfloat16 h = __float2bfloat16(f);
    return __builtin_bit_cast(short, h);
}
__device__ __forceinline__ float bs2f(short s) {
    __hip_bfloat16 h = __builtin_bit_cast(__hip_bfloat16, s);
    return __bfloat162float(h);
}

__global__ void detect_dtype(const void* w, int* flag) {
    const int lane = threadIdx.x;  // 64 threads
    const __hip_bfloat16* p = (const __hip_bfloat16*)w;
    const float v0 = __bfloat162float(p[lane]);
    const float v1 = __bfloat162float(p[64 + lane]);
    const bool bad = !(fabsf(v0) < 100.0f) || !(fabsf(v1) < 100.0f);
    const unsigned long long m = __ballot(bad);
    if (lane == 0) *flag = (__popcll(m) > 4) ? 1 : 0;  // 1 => data is fp32
}

template <bool F32>
__device__ __forceinline__ float ldg(const void* p, int idx) {
    if (F32) return ((const float*)p)[idx];
    return __bfloat162float(((const __hip_bfloat16*)p)[idx]);
}

template <bool F32>
__device__ void rnn_body(const void* __restrict__ xg, const void* __restrict__ h0,
                         const void* __restrict__ w0, const void* __restrict__ b0,
                         const void* __restrict__ W,  const void* __restrict__ bw,
                         const void* __restrict__ dw, const void* __restrict__ db,
                         void* __restrict__ out)
{
    __shared__ float xs[BM][TT + 1];                       // +1: kill 16-way bank conflict
    __shared__ __align__(16) __hip_bfloat16 hbuf[2][BM][HSTR];
    __shared__ __align__(16) float wpart[2][BM][NW];       // [t&1][batch][wave]

    const int tid  = threadIdx.x;
    const int lane = tid & 63;
    const int wv   = tid >> 6;        // 0..3
    const int q    = lane >> 4;       // 0..3
    const int n    = lane & 15;       // batch col (B-frag N, C-frag col, A-frag m)
    const int row0 = blockIdx.x * BM;

    // stage x (fp32 in LDS)
    for (int idx = tid; idx < BM * TT; idx += 256) {
        const int rr = idx >> 9, t2 = idx & (TT - 1);
        xs[rr][t2] = ldg<F32>(xg, (row0 + rr) * TT + t2);
    }
    // stage h0 as bf16
    for (int idx = tid; idx < BM * HH; idx += 256) {
        const int rr = idx >> 7, ii = idx & (HH - 1);
        hbuf[0][rr][ii] = __float2bfloat16(ldg<F32>(h0, (row0 + rr) * HH + ii));
    }

    // preload W fragments (A-operand: A[m=lane&15][k=q*8+j]), hi/lo split
    bf16x8 wa_hi[MTW][4], wa_lo[MTW][4];
    #pragma unroll
    for (int m2 = 0; m2 < MTW; ++m2) {
        const int ia = (wv * MTW + m2) * 16 + n;           // W row (output unit)
        #pragma unroll
        for (int kf = 0; kf < 4; ++kf) {
            const int kb = kf * 32 + q * 8;
            bf16x8 hi, lo;
            #pragma unroll
            for (int j = 0; j < 8; ++j) {
                const float f = ldg<F32>(W, ia * HH + kb + j);
                const short hs = f2bs(f);
                hi[j] = hs;
                lo[j] = F32 ? f2bs(f - bs2f(hs)) : (short)0;
            }
            wa_hi[m2][kf] = hi;
            wa_lo[m2][kf] = lo;
        }
    }
    // epilogue constants (C-layout rows: i = mt*16 + q*4 + r)
    float bsum[MTW][4], w0v[MTW][4], decv[MTW][4];
    #pragma unroll
    for (int m2 = 0; m2 < MTW; ++m2)
        #pragma unroll
        for (int r = 0; r < 4; ++r) {
            const int ic = (wv * MTW + m2) * 16 + q * 4 + r;
            bsum[m2][r] = ldg<F32>(b0, ic) + ldg<F32>(bw, ic);
            w0v[m2][r]  = ldg<F32>(w0, ic);
            decv[m2][r] = ldg<F32>(dw, ic);
        }
    const float dbv = ldg<F32>(db, 0);

    __syncthreads();

    int cur = 0;
    float ylast = 0.0f;
    #pragma unroll 1
    for (int t = 0; t < TOUT; ++t) {
        const float xv = (t < TT) ? xs[n][t] : ylast;
        // B-fragments: B[k=q*8+j][n] from h[batch n][k] (row-major, K contiguous)
        bf16x8 bfrag[4];
        #pragma unroll
        for (int kf = 0; kf < 4; ++kf)
            bfrag[kf] = *(const bf16x8*)&hbuf[cur][n][kf * 32 + q * 8];

        f32x4 acc[MTW][2];
        #pragma unroll
        for (int m2 = 0; m2 < MTW; ++m2) {
            acc[m2][0] = (f32x4){0.f, 0.f, 0.f, 0.f};
            acc[m2][1] = (f32x4){0.f, 0.f, 0.f, 0.f};
        }
        // 4 independent accumulation chains (2 m-tiles × hi/lo), K-depth 4 each
        #pragma unroll
        for (int kf = 0; kf < 4; ++kf) {
            #pragma unroll
            for (int m2 = 0; m2 < MTW; ++m2) {
                acc[m2][0] = __builtin_amdgcn_mfma_f32_16x16x32_bf16(
                    wa_hi[m2][kf], bfrag[kf], acc[m2][0], 0, 0, 0);
                if (F32)
                    acc[m2][1] = __builtin_amdgcn_mfma_f32_16x16x32_bf16(
                        wa_lo[m2][kf], bfrag[kf], acc[m2][1], 0, 0, 0);
            }
        }
        // epilogue: bias + x-term, tanh, pack bf16, decoder partial
        float p = 0.0f;
        #pragma unroll
        for (int m2 = 0; m2 < MTW; ++m2) {
            short4_t pk;
            #pragma unroll
            for (int r = 0; r < 4; ++r) {
                const float z = acc[m2][0][r] + acc[m2][1][r] + bsum[m2][r]
                              + xv * w0v[m2][r];
                const float e = __expf(z + z);
                const float h = 1.0f - 2.0f * __builtin_amdgcn_rcpf(e + 1.0f);
                p = fmaf(decv[m2][r], h, p);
                pk[r] = f2bs(h);
            }
            // h_new[batch n][i..i+3], 8B store
            *(short4_t*)&hbuf[cur ^ 1][n][(wv * MTW + m2) * 16 + q * 4] = pk;
        }
        p += __shfl_xor(p, 16);
        p += __shfl_xor(p, 32);
        if (q == 0) wpart[t & 1][n][wv] = p;
        __syncthreads();
        const f32x4 wp = *(const f32x4*)&wpart[t & 1][n][0];
        const float y = wp[0] + wp[1] + wp[2] + wp[3] + dbv;
        if (wv == 0 && q == 0) {
            const int o = (row0 + n) * TOUT + t;
            if (F32) ((float*)out)[o] = y;
            else     ((__hip_bfloat16*)out)[o] = __float2bfloat16(y);
        }
        ylast = y;
        cur ^= 1;
    }
}

__global__ __launch_bounds__(256, 1)
void rnn_mfma(const void* __restrict__ xg, const void* __restrict__ h0,
              const void* __restrict__ w0, const void* __restrict__ b0,
              const void* __restrict__ W,  const void* __restrict__ bw,
              const void* __restrict__ dw, const void* __restrict__ db,
              void* __restrict__ out, const int* __restrict__ flag)
{
    const int f = *(volatile const int*)flag;  // block-uniform
    if (f) rnn_body<true >(xg, h0, w0, b0, W, bw, dw, db, out);
    else   rnn_body<false>(xg, h0, w0, b0, W, bw, dw, db, out);
}

extern "C" void kernel_launch(void* const* d_in, const int* in_sizes, int n_in,
                              void* d_out, int out_size, void* d_ws, size_t ws_size,
                              hipStream_t stream) {
    int* flag = (int*)d_ws;
    detect_dtype<<<1, 64, 0, stream>>>(d_in[4], flag);  // probe fc_w
    rnn_mfma<<<BB / BM, 256, 0, stream>>>(d_in[0], d_in[1], d_in[2], d_in[3],
                                          d_in[4], d_in[5], d_in[6], d_in[7],
                                          d_out, flag);
}